// Round 3
// baseline (3738.790 us; speedup 1.0000x reference)
//
#include <hip/hip_runtime.h>
#include <math.h>

#define N_TOT 32768
#define K_CB 8192
#define D_DIM 256
#define K_EFF 768
#define BK 64
#define STAGES 12

#define OUT_IDX  (N_TOT * D_DIM)   // 8388608
#define OUT_LOSS (OUT_IDX + N_TOT) // 8421376
#define OUT_PERP (OUT_LOSS + 1)

typedef __attribute__((ext_vector_type(8))) short bf16x8;
typedef __attribute__((ext_vector_type(4))) float f32x4;

__device__ __forceinline__ unsigned short f2bf_rne(float x) {
  unsigned int u = __float_as_uint(x);
  unsigned int r = u + 0x7FFF + ((u >> 16) & 1);
  return (unsigned short)(r >> 16);
}

__device__ __forceinline__ void gl2lds16(const void* g, void* lds) {
  __builtin_amdgcn_global_load_lds(
      (const __attribute__((address_space(1))) unsigned int*)g,
      (__attribute__((address_space(3))) unsigned int*)lds, 16, 0, 0);
}

__device__ __forceinline__ void top2_merge(float& d1, int& i1, float& d2, int& i2,
                                           float nd, int ni) {
  if (nd < d1 || (nd == d1 && ni < i1)) { d2 = d1; i2 = i1; d1 = nd; i1 = ni; }
  else if (nd < d2 || (nd == d2 && ni < i2)) { d2 = nd; i2 = ni; }
}

// Swizzled slot for logical 8-elem chunk `L` of row `r`: permute within each
// 8-chunk (128 B) group so argmin_gemm's global_load_lds reads are lane-linear
// while ds_read fragments stay bank-conflict-free.
__device__ __forceinline__ int swz_slot(int chunk, int r) {
  return ((chunk & ~7) | ((chunk & 7) ^ (r & 7))) << 3;  // element offset
}

// ---------------- bf16 hi/lo split: A' = [Zhi|Zhi|Zlo] (pre-swizzled) ----------------
__global__ __launch_bounds__(256) void split_z_kernel(const float* __restrict__ Z,
                                                      short* __restrict__ Ap) {
  const int g = blockIdx.x * 256 + threadIdx.x;   // one 8-elem group
  const int row = g >> 5;
  const int cc = g & 31;                          // logical chunk within D
  const int seg = cc << 3;
  const float4 v0 = *(const float4*)(Z + (size_t)row * D_DIM + seg);
  const float4 v1 = *(const float4*)(Z + (size_t)row * D_DIM + seg + 4);
  float vv[8] = {v0.x, v0.y, v0.z, v0.w, v1.x, v1.y, v1.z, v1.w};
  bf16x8 hv, lv;
#pragma unroll
  for (int j = 0; j < 8; j++) {
    const unsigned short h = f2bf_rne(vv[j]);
    const float hf = __uint_as_float(((unsigned)h) << 16);
    hv[j] = (short)h;
    lv[j] = (short)f2bf_rne(vv[j] - hf);
  }
  short* base = Ap + (size_t)row * K_EFF;
  *(bf16x8*)(base + swz_slot(cc, row))      = hv;
  *(bf16x8*)(base + swz_slot(cc + 32, row)) = hv;
  *(bf16x8*)(base + swz_slot(cc + 64, row)) = lv;
}

// ---------------- bf16 hi/lo split: B' = [Ehi|Elo|Ehi] (pre-swizzled) ----------------
__global__ __launch_bounds__(256) void split_e_kernel(const float* __restrict__ E,
                                                      short* __restrict__ Bp) {
  const int g = blockIdx.x * 256 + threadIdx.x;
  const int row = g >> 5;
  const int cc = g & 31;
  const int seg = cc << 3;
  const float4 v0 = *(const float4*)(E + (size_t)row * D_DIM + seg);
  const float4 v1 = *(const float4*)(E + (size_t)row * D_DIM + seg + 4);
  float vv[8] = {v0.x, v0.y, v0.z, v0.w, v1.x, v1.y, v1.z, v1.w};
  bf16x8 hv, lv;
#pragma unroll
  for (int j = 0; j < 8; j++) {
    const unsigned short h = f2bf_rne(vv[j]);
    const float hf = __uint_as_float(((unsigned)h) << 16);
    hv[j] = (short)h;
    lv[j] = (short)f2bf_rne(vv[j] - hf);
  }
  short* base = Bp + (size_t)row * K_EFF;
  *(bf16x8*)(base + swz_slot(cc, row))      = hv;
  *(bf16x8*)(base + swz_slot(cc + 32, row)) = lv;
  *(bf16x8*)(base + swz_slot(cc + 64, row)) = hv;
}

// ---------------- e_sq (exact fp32) ----------------
__global__ __launch_bounds__(256) void esq_kernel(const float* __restrict__ E,
                                                  float* __restrict__ esq) {
  const int c = blockIdx.x * 4 + (threadIdx.x >> 6);
  const int lane = threadIdx.x & 63;
  const float4 v = *(const float4*)(E + (size_t)c * D_DIM + lane * 4);
  float s = v.x * v.x + v.y * v.y + v.z * v.z + v.w * v.w;
#pragma unroll
  for (int off = 32; off > 0; off >>= 1) s += __shfl_down(s, off);
  if (lane == 0) esq[c] = s;
}

// ---------------- MFMA dist GEMM + per-block top-2 partials ----------------
// dist = e_sq[c] - 2*dot(z,e); dot via K_EFF=768 split-bf16 GEMM.
// Grid (mb=x over N rows, nb=y over codes): consecutive blocks share the B-tile.
__global__ __launch_bounds__(256) void argmin_gemm_kernel(
    const short* __restrict__ Ap, const short* __restrict__ Bp,
    const float* __restrict__ esq, float4* __restrict__ partials) {
  __shared__ __align__(16) union U {
    struct { short A[128 * BK]; short B[128 * BK]; } s;   // 32 KB, rows pre-swizzled
    struct { float4 red[128][2]; } r;                     // epilogue
  } u;
  __shared__ float esq_s[128];

  const int tid = threadIdx.x;
  const int mb = blockIdx.x, nb = blockIdx.y;
  const int w = tid >> 6, lane = tid & 63;
  const int wr = w >> 1, wc = w & 1;
  const int l15 = lane & 15, quad = lane >> 4;

  if (tid < 128) esq_s[tid] = esq[nb * 128 + tid];

  f32x4 acc[4][4];
#pragma unroll
  for (int i = 0; i < 4; i++)
#pragma unroll
    for (int j = 0; j < 4; j++) acc[i][j] = (f32x4){0.f, 0.f, 0.f, 0.f};

  for (int s = 0; s < STAGES; s++) {
    __syncthreads();  // previous stage's ds_reads complete before overwrite
#pragma unroll
    for (int i = 0; i < 4; i++) {
      const int g = i * 256 + tid;          // chunk id 0..1023
      const int r = g >> 3;                 // tile row 0..127
      const int c = g & 7;                  // slot (swizzle baked into buffer)
      gl2lds16(Ap + ((size_t)(mb * 128 + r) * K_EFF + s * BK + c * 8),
               (char*)u.s.A + g * 16);
      gl2lds16(Bp + ((size_t)(nb * 128 + r) * K_EFF + s * BK + c * 8),
               (char*)u.s.B + g * 16);
    }
    __syncthreads();  // drains vmcnt: LDS tiles ready
#pragma unroll
    for (int ks = 0; ks < 2; ks++) {
      bf16x8 af[4], bf[4];
#pragma unroll
      for (int ti = 0; ti < 4; ti++) {
        const int rowA = wr * 64 + ti * 16 + l15;
        const int swa = (ks * 4 + quad) ^ (rowA & 7);
        af[ti] = *(const bf16x8*)((const char*)u.s.A + rowA * 128 + swa * 16);
        const int rowB = wc * 64 + ti * 16 + l15;
        const int swb = (ks * 4 + quad) ^ (rowB & 7);
        bf[ti] = *(const bf16x8*)((const char*)u.s.B + rowB * 128 + swb * 16);
      }
#pragma unroll
      for (int ti = 0; ti < 4; ti++)
#pragma unroll
        for (int tj = 0; tj < 4; tj++)
          acc[ti][tj] = __builtin_amdgcn_mfma_f32_16x16x32_bf16(
              af[ti], bf[tj], acc[ti][tj], 0, 0, 0);
    }
  }

  __syncthreads();  // all LDS compute reads done; reuse union for reduction
  // C layout: row = quad*4 + reg, col = lane&15 (per 16x16 tile)
#pragma unroll
  for (int ti = 0; ti < 4; ti++) {
#pragma unroll
    for (int reg = 0; reg < 4; reg++) {
      float d1 = 3.4e38f, d2 = 3.4e38f;
      int i1 = 0, i2 = 0;
#pragma unroll
      for (int tj = 0; tj < 4; tj++) {
        const float dist = esq_s[wc * 64 + tj * 16 + l15] - 2.0f * acc[ti][tj][reg];
        const int c = nb * 128 + wc * 64 + tj * 16 + l15;
        top2_merge(d1, i1, d2, i2, dist, c);
      }
#pragma unroll
      for (int m = 1; m <= 8; m <<= 1) {
        const float od1 = __shfl_xor(d1, m); const int oi1 = __shfl_xor(i1, m);
        const float od2 = __shfl_xor(d2, m); const int oi2 = __shfl_xor(i2, m);
        top2_merge(d1, i1, d2, i2, od1, oi1);
        top2_merge(d1, i1, d2, i2, od2, oi2);
      }
      if (l15 == 0) {
        const int row_local = wr * 64 + ti * 16 + quad * 4 + reg;
        u.r.red[row_local][wc] =
            make_float4(d1, __int_as_float(i1), d2, __int_as_float(i2));
      }
    }
  }
  __syncthreads();
  if (tid < 128) {
    const float4 pa = u.r.red[tid][0];
    const float4 pb = u.r.red[tid][1];
    float d1 = pa.x, d2 = pa.z;
    int i1 = __float_as_int(pa.y), i2 = __float_as_int(pa.w);
    top2_merge(d1, i1, d2, i2, pb.x, __float_as_int(pb.y));
    top2_merge(d1, i1, d2, i2, pb.z, __float_as_int(pb.w));
    partials[(size_t)(mb * 128 + tid) * 64 + nb] =
        make_float4(d1, __int_as_float(i1), d2, __int_as_float(i2));
  }
}

// ---------------- merge 64 partials/row + distributed fp64 rescore ----------------
__global__ __launch_bounds__(256) void reduce_kernel(
    const float4* __restrict__ partials, const float* __restrict__ Z,
    const float* __restrict__ E, float* __restrict__ out_idx_f) {
  const int row = blockIdx.x * 4 + (threadIdx.x >> 6);
  const int lane = threadIdx.x & 63;
  const float4 p = partials[(size_t)row * 64 + lane];
  float d1 = p.x, d2 = p.z;
  int i1 = __float_as_int(p.y), i2 = __float_as_int(p.w);
#pragma unroll
  for (int m = 1; m < 64; m <<= 1) {
    const float od1 = __shfl_xor(d1, m); const int oi1 = __shfl_xor(i1, m);
    const float od2 = __shfl_xor(d2, m); const int oi2 = __shfl_xor(i2, m);
    top2_merge(d1, i1, d2, i2, od1, oi1);
    top2_merge(d1, i1, d2, i2, od2, oi2);
  }
  // all lanes hold the same global top-2; fp64 rescore split across lanes
  const float4 zv  = ((const float4*)(Z + (size_t)row * D_DIM))[lane];
  const float4 e1v = ((const float4*)(E + (size_t)i1 * D_DIM))[lane];
  const float4 e2v = ((const float4*)(E + (size_t)i2 * D_DIM))[lane];
  double a = 0.0, b = 0.0, t;
  t = (double)zv.x - (double)e1v.x; a += t * t;
  t = (double)zv.y - (double)e1v.y; a += t * t;
  t = (double)zv.z - (double)e1v.z; a += t * t;
  t = (double)zv.w - (double)e1v.w; a += t * t;
  t = (double)zv.x - (double)e2v.x; b += t * t;
  t = (double)zv.y - (double)e2v.y; b += t * t;
  t = (double)zv.z - (double)e2v.z; b += t * t;
  t = (double)zv.w - (double)e2v.w; b += t * t;
#pragma unroll
  for (int m = 1; m < 64; m <<= 1) {
    a += __shfl_xor(a, m);
    b += __shfl_xor(b, m);
  }
  if (lane == 0) {
    const int fin = (b < a || (b == a && i2 < i1)) ? i2 : i1;
    out_idx_f[row] = (float)fin;
  }
}

// ---------------- gather z_q, accumulate loss sum + counts ----------------
__global__ __launch_bounds__(256) void gather_kernel(
    const float* __restrict__ Z, const float* __restrict__ E,
    const float* __restrict__ idx_f, float* __restrict__ zq_out,
    float* __restrict__ counts, float* __restrict__ loss_sum) {
  const int row = blockIdx.x;
  const int t = threadIdx.x;
  const int c = (int)idx_f[row];
  const float e = E[(size_t)c * D_DIM + t];
  const float z = Z[(size_t)row * D_DIM + t];
  zq_out[(size_t)row * D_DIM + t] = e;
  float sq = (z - e) * (z - e);
#pragma unroll
  for (int off = 32; off > 0; off >>= 1) sq += __shfl_down(sq, off);
  __shared__ float wsum[4];
  if ((t & 63) == 0) wsum[t >> 6] = sq;
  __syncthreads();
  if (t == 0) {
    atomicAdd(loss_sum, wsum[0] + wsum[1] + wsum[2] + wsum[3]);
    atomicAdd(&counts[c], 1.0f);
  }
}

// ---------------- loss scale + perplexity ----------------
__global__ __launch_bounds__(256) void final_kernel(
    const float* __restrict__ counts, const float* __restrict__ loss_sum,
    float* __restrict__ out) {
  const int t = threadIdx.x;
  float h = 0.0f;
  for (int k = t; k < K_CB; k += 256) {
    const float p = counts[k] * (1.0f / (float)N_TOT);
    h += p * logf(p + 1e-12f);
  }
#pragma unroll
  for (int off = 32; off > 0; off >>= 1) h += __shfl_down(h, off);
  __shared__ float ws4[4];
  if ((t & 63) == 0) ws4[t >> 6] = h;
  __syncthreads();
  if (t == 0) {
    const float H = ws4[0] + ws4[1] + ws4[2] + ws4[3];
    out[OUT_LOSS] = 1.25f * loss_sum[0] * (1.0f / (float)(N_TOT * D_DIM));
    out[OUT_PERP] = expf(-H);
  }
}

extern "C" void kernel_launch(void* const* d_in, const int* in_sizes, int n_in,
                              void* d_out, int out_size, void* d_ws, size_t ws_size,
                              hipStream_t stream) {
  (void)in_sizes; (void)n_in; (void)out_size; (void)ws_size;
  const float* Z = (const float*)d_in[0];
  const float* E = (const float*)d_in[1];
  float* out = (float*)d_out;
  char* ws = (char*)d_ws;
  float* counts   = (float*)ws;                      // 32 KB
  float* loss_sum = (float*)(ws + 32768);            // 4 B
  float* esq      = (float*)(ws + 36864);            // 32 KB
  short* Ap       = (short*)(ws + 69632);            // 32768*768*2 = 50331648 B
  short* Bp       = (short*)(ws + 69632 + 50331648); // 8192*768*2  = 12582912 B
  // partials live in d_out's zq region (exactly 32768*64 float4), overwritten by gather later
  float4* partials = (float4*)d_out;

  hipMemsetAsync(ws, 0, 32772, stream);  // zero counts + loss_sum
  esq_kernel<<<dim3(K_CB / 4), dim3(256), 0, stream>>>(E, esq);
  split_z_kernel<<<dim3(N_TOT * D_DIM / 8 / 256), dim3(256), 0, stream>>>(Z, Ap);
  split_e_kernel<<<dim3(K_CB * D_DIM / 8 / 256), dim3(256), 0, stream>>>(E, Bp);
  argmin_gemm_kernel<<<dim3(N_TOT / 128, K_CB / 128), dim3(256), 0, stream>>>(
      Ap, Bp, esq, partials);
  reduce_kernel<<<dim3(N_TOT / 4), dim3(256), 0, stream>>>(partials, Z, E, out + OUT_IDX);
  gather_kernel<<<dim3(N_TOT), dim3(256), 0, stream>>>(Z, E, out + OUT_IDX, out, counts, loss_sum);
  final_kernel<<<dim3(1), dim3(256), 0, stream>>>(counts, loss_sum, out);
}

// Round 4
// 3657.686 us; speedup vs baseline: 1.0222x; 1.0222x over previous
//
#include <hip/hip_runtime.h>
#include <math.h>

#define N_TOT 32768
#define K_CB 8192
#define D_DIM 256
#define K_EFF 768
#define BK 64
#define STAGES 12

#define OUT_IDX  (N_TOT * D_DIM)   // 8388608
#define OUT_LOSS (OUT_IDX + N_TOT) // 8421376
#define OUT_PERP (OUT_LOSS + 1)

typedef __attribute__((ext_vector_type(8))) short bf16x8;
typedef __attribute__((ext_vector_type(4))) float f32x4;

__device__ __forceinline__ unsigned short f2bf_rne(float x) {
  unsigned int u = __float_as_uint(x);
  unsigned int r = u + 0x7FFF + ((u >> 16) & 1);
  return (unsigned short)(r >> 16);
}

__device__ __forceinline__ void gl2lds16(const void* g, void* lds) {
  __builtin_amdgcn_global_load_lds(
      (const __attribute__((address_space(1))) unsigned int*)g,
      (__attribute__((address_space(3))) unsigned int*)lds, 16, 0, 0);
}

__device__ __forceinline__ void top2_merge(float& d1, int& i1, float& d2, int& i2,
                                           float nd, int ni) {
  if (nd < d1 || (nd == d1 && ni < i1)) { d2 = d1; i2 = i1; d1 = nd; i1 = ni; }
  else if (nd < d2 || (nd == d2 && ni < i2)) { d2 = nd; i2 = ni; }
}

// Swizzled slot for logical 8-elem chunk `L` of row `r`: permute within each
// 8-chunk (128 B) group so argmin_gemm's global_load_lds reads are lane-linear
// while ds_read fragments stay bank-conflict-free.
__device__ __forceinline__ int swz_slot(int chunk, int r) {
  return ((chunk & ~7) | ((chunk & 7) ^ (r & 7))) << 3;  // element offset
}

// ---------------- bf16 hi/lo split: A' = [Zhi|Zhi|Zlo] (pre-swizzled) ----------------
__global__ __launch_bounds__(256) void split_z_kernel(const float* __restrict__ Z,
                                                      short* __restrict__ Ap) {
  const int g = blockIdx.x * 256 + threadIdx.x;   // one 8-elem group
  const int row = g >> 5;
  const int cc = g & 31;                          // logical chunk within D
  const int seg = cc << 3;
  const float4 v0 = *(const float4*)(Z + (size_t)row * D_DIM + seg);
  const float4 v1 = *(const float4*)(Z + (size_t)row * D_DIM + seg + 4);
  float vv[8] = {v0.x, v0.y, v0.z, v0.w, v1.x, v1.y, v1.z, v1.w};
  bf16x8 hv, lv;
#pragma unroll
  for (int j = 0; j < 8; j++) {
    const unsigned short h = f2bf_rne(vv[j]);
    const float hf = __uint_as_float(((unsigned)h) << 16);
    hv[j] = (short)h;
    lv[j] = (short)f2bf_rne(vv[j] - hf);
  }
  short* base = Ap + (size_t)row * K_EFF;
  *(bf16x8*)(base + swz_slot(cc, row))      = hv;
  *(bf16x8*)(base + swz_slot(cc + 32, row)) = hv;
  *(bf16x8*)(base + swz_slot(cc + 64, row)) = lv;
}

// ---------------- bf16 hi/lo split: B' = [Ehi|Elo|Ehi] (pre-swizzled) ----------------
__global__ __launch_bounds__(256) void split_e_kernel(const float* __restrict__ E,
                                                      short* __restrict__ Bp) {
  const int g = blockIdx.x * 256 + threadIdx.x;
  const int row = g >> 5;
  const int cc = g & 31;
  const int seg = cc << 3;
  const float4 v0 = *(const float4*)(E + (size_t)row * D_DIM + seg);
  const float4 v1 = *(const float4*)(E + (size_t)row * D_DIM + seg + 4);
  float vv[8] = {v0.x, v0.y, v0.z, v0.w, v1.x, v1.y, v1.z, v1.w};
  bf16x8 hv, lv;
#pragma unroll
  for (int j = 0; j < 8; j++) {
    const unsigned short h = f2bf_rne(vv[j]);
    const float hf = __uint_as_float(((unsigned)h) << 16);
    hv[j] = (short)h;
    lv[j] = (short)f2bf_rne(vv[j] - hf);
  }
  short* base = Bp + (size_t)row * K_EFF;
  *(bf16x8*)(base + swz_slot(cc, row))      = hv;
  *(bf16x8*)(base + swz_slot(cc + 32, row)) = lv;
  *(bf16x8*)(base + swz_slot(cc + 64, row)) = hv;
}

// ---------------- e_sq (exact fp32) ----------------
__global__ __launch_bounds__(256) void esq_kernel(const float* __restrict__ E,
                                                  float* __restrict__ esq) {
  const int c = blockIdx.x * 4 + (threadIdx.x >> 6);
  const int lane = threadIdx.x & 63;
  const float4 v = *(const float4*)(E + (size_t)c * D_DIM + lane * 4);
  float s = v.x * v.x + v.y * v.y + v.z * v.z + v.w * v.w;
#pragma unroll
  for (int off = 32; off > 0; off >>= 1) s += __shfl_down(s, off);
  if (lane == 0) esq[c] = s;
}

// ---------------- MFMA dist GEMM + per-block top-2 partials ----------------
// dist = e_sq[c] - 2*dot(z,e); dot via K_EFF=768 split-bf16 GEMM.
// Grid: x=nb (codes, fastest) so B' stays L3/L2-resident and A' is read ~once.
__global__ __launch_bounds__(256) void argmin_gemm_kernel(
    const short* __restrict__ Ap, const short* __restrict__ Bp,
    const float* __restrict__ esq, float4* __restrict__ partials) {
  __shared__ __align__(16) union U {
    struct { short A[128 * BK]; short B[128 * BK]; } s;   // 32 KB, rows pre-swizzled
    struct { float4 red[128][2]; } r;                     // epilogue
  } u;
  __shared__ float esq_s[128];

  const int tid = threadIdx.x;
  const int nb = blockIdx.x, mb = blockIdx.y;
  const int w = tid >> 6, lane = tid & 63;
  const int wr = w >> 1, wc = w & 1;
  const int l15 = lane & 15, quad = lane >> 4;

  if (tid < 128) esq_s[tid] = esq[nb * 128 + tid];

  f32x4 acc[4][4];
#pragma unroll
  for (int i = 0; i < 4; i++)
#pragma unroll
    for (int j = 0; j < 4; j++) acc[i][j] = (f32x4){0.f, 0.f, 0.f, 0.f};

  for (int s = 0; s < STAGES; s++) {
    __syncthreads();  // previous stage's ds_reads complete before overwrite
#pragma unroll
    for (int i = 0; i < 4; i++) {
      const int gw = i * 256 + (tid & ~63);   // wave-uniform chunk base
      // WAVE-UNIFORM LDS base (readfirstlane): HW adds lane*16 itself.
      // A divergent lds operand forces an LLVM waterfall loop = 64x serialization.
      const int ldsb = __builtin_amdgcn_readfirstlane(gw << 4);
      const int g = gw + lane;                // this lane's chunk
      const int r = g >> 3;                   // tile row 0..127
      const int c = g & 7;                    // slot (swizzle baked into buffer)
      gl2lds16(Ap + ((size_t)(mb * 128 + r) * K_EFF + s * BK + c * 8),
               (char*)u.s.A + ldsb);
      gl2lds16(Bp + ((size_t)(nb * 128 + r) * K_EFF + s * BK + c * 8),
               (char*)u.s.B + ldsb);
    }
    __syncthreads();  // drains vmcnt: LDS tiles ready
#pragma unroll
    for (int ks = 0; ks < 2; ks++) {
      bf16x8 af[4], bf[4];
#pragma unroll
      for (int ti = 0; ti < 4; ti++) {
        const int rowA = wr * 64 + ti * 16 + l15;
        const int swa = (ks * 4 + quad) ^ (rowA & 7);
        af[ti] = *(const bf16x8*)((const char*)u.s.A + rowA * 128 + swa * 16);
        const int rowB = wc * 64 + ti * 16 + l15;
        const int swb = (ks * 4 + quad) ^ (rowB & 7);
        bf[ti] = *(const bf16x8*)((const char*)u.s.B + rowB * 128 + swb * 16);
      }
#pragma unroll
      for (int ti = 0; ti < 4; ti++)
#pragma unroll
        for (int tj = 0; tj < 4; tj++)
          acc[ti][tj] = __builtin_amdgcn_mfma_f32_16x16x32_bf16(
              af[ti], bf[tj], acc[ti][tj], 0, 0, 0);
    }
  }

  __syncthreads();  // all LDS compute reads done; reuse union for reduction
  // C layout: row = quad*4 + reg, col = lane&15 (per 16x16 tile)
#pragma unroll
  for (int ti = 0; ti < 4; ti++) {
#pragma unroll
    for (int reg = 0; reg < 4; reg++) {
      float d1 = 3.4e38f, d2 = 3.4e38f;
      int i1 = 0, i2 = 0;
#pragma unroll
      for (int tj = 0; tj < 4; tj++) {
        const float dist = esq_s[wc * 64 + tj * 16 + l15] - 2.0f * acc[ti][tj][reg];
        const int c = nb * 128 + wc * 64 + tj * 16 + l15;
        top2_merge(d1, i1, d2, i2, dist, c);
      }
#pragma unroll
      for (int m = 1; m <= 8; m <<= 1) {
        const float od1 = __shfl_xor(d1, m); const int oi1 = __shfl_xor(i1, m);
        const float od2 = __shfl_xor(d2, m); const int oi2 = __shfl_xor(i2, m);
        top2_merge(d1, i1, d2, i2, od1, oi1);
        top2_merge(d1, i1, d2, i2, od2, oi2);
      }
      if (l15 == 0) {
        const int row_local = wr * 64 + ti * 16 + quad * 4 + reg;
        u.r.red[row_local][wc] =
            make_float4(d1, __int_as_float(i1), d2, __int_as_float(i2));
      }
    }
  }
  __syncthreads();
  if (tid < 128) {
    const float4 pa = u.r.red[tid][0];
    const float4 pb = u.r.red[tid][1];
    float d1 = pa.x, d2 = pa.z;
    int i1 = __float_as_int(pa.y), i2 = __float_as_int(pa.w);
    top2_merge(d1, i1, d2, i2, pb.x, __float_as_int(pb.y));
    top2_merge(d1, i1, d2, i2, pb.z, __float_as_int(pb.w));
    partials[(size_t)(mb * 128 + tid) * 64 + nb] =
        make_float4(d1, __int_as_float(i1), d2, __int_as_float(i2));
  }
}

// ---------------- merge 64 partials/row + distributed fp64 rescore ----------------
__global__ __launch_bounds__(256) void reduce_kernel(
    const float4* __restrict__ partials, const float* __restrict__ Z,
    const float* __restrict__ E, float* __restrict__ out_idx_f) {
  const int row = blockIdx.x * 4 + (threadIdx.x >> 6);
  const int lane = threadIdx.x & 63;
  const float4 p = partials[(size_t)row * 64 + lane];
  float d1 = p.x, d2 = p.z;
  int i1 = __float_as_int(p.y), i2 = __float_as_int(p.w);
#pragma unroll
  for (int m = 1; m < 64; m <<= 1) {
    const float od1 = __shfl_xor(d1, m); const int oi1 = __shfl_xor(i1, m);
    const float od2 = __shfl_xor(d2, m); const int oi2 = __shfl_xor(i2, m);
    top2_merge(d1, i1, d2, i2, od1, oi1);
    top2_merge(d1, i1, d2, i2, od2, oi2);
  }
  // all lanes hold the same global top-2; fp64 rescore split across lanes
  const float4 zv  = ((const float4*)(Z + (size_t)row * D_DIM))[lane];
  const float4 e1v = ((const float4*)(E + (size_t)i1 * D_DIM))[lane];
  const float4 e2v = ((const float4*)(E + (size_t)i2 * D_DIM))[lane];
  double a = 0.0, b = 0.0, t;
  t = (double)zv.x - (double)e1v.x; a += t * t;
  t = (double)zv.y - (double)e1v.y; a += t * t;
  t = (double)zv.z - (double)e1v.z; a += t * t;
  t = (double)zv.w - (double)e1v.w; a += t * t;
  t = (double)zv.x - (double)e2v.x; b += t * t;
  t = (double)zv.y - (double)e2v.y; b += t * t;
  t = (double)zv.z - (double)e2v.z; b += t * t;
  t = (double)zv.w - (double)e2v.w; b += t * t;
#pragma unroll
  for (int m = 1; m < 64; m <<= 1) {
    a += __shfl_xor(a, m);
    b += __shfl_xor(b, m);
  }
  if (lane == 0) {
    const int fin = (b < a || (b == a && i2 < i1)) ? i2 : i1;
    out_idx_f[row] = (float)fin;
  }
}

// ---------------- gather z_q, accumulate loss sum + counts ----------------
__global__ __launch_bounds__(256) void gather_kernel(
    const float* __restrict__ Z, const float* __restrict__ E,
    const float* __restrict__ idx_f, float* __restrict__ zq_out,
    float* __restrict__ counts, float* __restrict__ loss_sum) {
  const int row = blockIdx.x;
  const int t = threadIdx.x;
  const int c = (int)idx_f[row];
  const float e = E[(size_t)c * D_DIM + t];
  const float z = Z[(size_t)row * D_DIM + t];
  zq_out[(size_t)row * D_DIM + t] = e;
  float sq = (z - e) * (z - e);
#pragma unroll
  for (int off = 32; off > 0; off >>= 1) sq += __shfl_down(sq, off);
  __shared__ float wsum[4];
  if ((t & 63) == 0) wsum[t >> 6] = sq;
  __syncthreads();
  if (t == 0) {
    atomicAdd(loss_sum, wsum[0] + wsum[1] + wsum[2] + wsum[3]);
    atomicAdd(&counts[c], 1.0f);
  }
}

// ---------------- loss scale + perplexity ----------------
__global__ __launch_bounds__(256) void final_kernel(
    const float* __restrict__ counts, const float* __restrict__ loss_sum,
    float* __restrict__ out) {
  const int t = threadIdx.x;
  float h = 0.0f;
  for (int k = t; k < K_CB; k += 256) {
    const float p = counts[k] * (1.0f / (float)N_TOT);
    h += p * logf(p + 1e-12f);
  }
#pragma unroll
  for (int off = 32; off > 0; off >>= 1) h += __shfl_down(h, off);
  __shared__ float ws4[4];
  if ((t & 63) == 0) ws4[t >> 6] = h;
  __syncthreads();
  if (t == 0) {
    const float H = ws4[0] + ws4[1] + ws4[2] + ws4[3];
    out[OUT_LOSS] = 1.25f * loss_sum[0] * (1.0f / (float)(N_TOT * D_DIM));
    out[OUT_PERP] = expf(-H);
  }
}

extern "C" void kernel_launch(void* const* d_in, const int* in_sizes, int n_in,
                              void* d_out, int out_size, void* d_ws, size_t ws_size,
                              hipStream_t stream) {
  (void)in_sizes; (void)n_in; (void)out_size; (void)ws_size;
  const float* Z = (const float*)d_in[0];
  const float* E = (const float*)d_in[1];
  float* out = (float*)d_out;
  char* ws = (char*)d_ws;
  float* counts   = (float*)ws;                      // 32 KB
  float* loss_sum = (float*)(ws + 32768);            // 4 B
  float* esq      = (float*)(ws + 36864);            // 32 KB
  short* Ap       = (short*)(ws + 69632);            // 32768*768*2 = 50331648 B
  short* Bp       = (short*)(ws + 69632 + 50331648); // 8192*768*2  = 12582912 B
  // partials live in d_out's zq region (exactly 32768*64 float4), overwritten by gather later
  float4* partials = (float4*)d_out;

  hipMemsetAsync(ws, 0, 32772, stream);  // zero counts + loss_sum
  esq_kernel<<<dim3(K_CB / 4), dim3(256), 0, stream>>>(E, esq);
  split_z_kernel<<<dim3(N_TOT * D_DIM / 8 / 256), dim3(256), 0, stream>>>(Z, Ap);
  split_e_kernel<<<dim3(K_CB * D_DIM / 8 / 256), dim3(256), 0, stream>>>(E, Bp);
  argmin_gemm_kernel<<<dim3(K_CB / 128, N_TOT / 128), dim3(256), 0, stream>>>(
      Ap, Bp, esq, partials);
  reduce_kernel<<<dim3(N_TOT / 4), dim3(256), 0, stream>>>(partials, Z, E, out + OUT_IDX);
  gather_kernel<<<dim3(N_TOT), dim3(256), 0, stream>>>(Z, E, out + OUT_IDX, out, counts, loss_sum);
  final_kernel<<<dim3(1), dim3(256), 0, stream>>>(counts, loss_sum, out);
}

// Round 5
// 3640.281 us; speedup vs baseline: 1.0271x; 1.0048x over previous
//
#include <hip/hip_runtime.h>
#include <math.h>

#define N_TOT 32768
#define K_CB 8192
#define D_DIM 256
#define K_EFF 768
#define BK 64
#define STAGES 12

#define OUT_IDX  (N_TOT * D_DIM)   // 8388608
#define OUT_LOSS (OUT_IDX + N_TOT) // 8421376
#define OUT_PERP (OUT_LOSS + 1)

typedef __attribute__((ext_vector_type(8))) short bf16x8;
typedef __attribute__((ext_vector_type(4))) float f32x4;

__device__ __forceinline__ unsigned short f2bf_rne(float x) {
  unsigned int u = __float_as_uint(x);
  unsigned int r = u + 0x7FFF + ((u >> 16) & 1);
  return (unsigned short)(r >> 16);
}

__device__ __forceinline__ void top2_merge(float& d1, int& i1, float& d2, int& i2,
                                           float nd, int ni) {
  if (nd < d1 || (nd == d1 && ni < i1)) { d2 = d1; i2 = i1; d1 = nd; i1 = ni; }
  else if (nd < d2 || (nd == d2 && ni < i2)) { d2 = nd; i2 = ni; }
}

// Swizzled slot for logical 8-elem chunk `L` of row `r`: permute within each
// 8-chunk (128 B) group so LDS-stage layout == global layout (identity copy)
// while ds_read fragments stay bank-conflict-free.
__device__ __forceinline__ int swz_slot(int chunk, int r) {
  return ((chunk & ~7) | ((chunk & 7) ^ (r & 7))) << 3;  // element offset
}

// ---------------- bf16 hi/lo split: A' = [Zhi|Zhi|Zlo] (pre-swizzled) ----------------
__global__ __launch_bounds__(256) void split_z_kernel(const float* __restrict__ Z,
                                                      short* __restrict__ Ap) {
  const int g = blockIdx.x * 256 + threadIdx.x;   // one 8-elem group
  const int row = g >> 5;
  const int cc = g & 31;                          // logical chunk within D
  const int seg = cc << 3;
  const float4 v0 = *(const float4*)(Z + (size_t)row * D_DIM + seg);
  const float4 v1 = *(const float4*)(Z + (size_t)row * D_DIM + seg + 4);
  float vv[8] = {v0.x, v0.y, v0.z, v0.w, v1.x, v1.y, v1.z, v1.w};
  bf16x8 hv, lv;
#pragma unroll
  for (int j = 0; j < 8; j++) {
    const unsigned short h = f2bf_rne(vv[j]);
    const float hf = __uint_as_float(((unsigned)h) << 16);
    hv[j] = (short)h;
    lv[j] = (short)f2bf_rne(vv[j] - hf);
  }
  short* base = Ap + (size_t)row * K_EFF;
  *(bf16x8*)(base + swz_slot(cc, row))      = hv;
  *(bf16x8*)(base + swz_slot(cc + 32, row)) = hv;
  *(bf16x8*)(base + swz_slot(cc + 64, row)) = lv;
}

// ---------------- bf16 hi/lo split: B' = [Ehi|Elo|Ehi] (pre-swizzled) ----------------
__global__ __launch_bounds__(256) void split_e_kernel(const float* __restrict__ E,
                                                      short* __restrict__ Bp) {
  const int g = blockIdx.x * 256 + threadIdx.x;
  const int row = g >> 5;
  const int cc = g & 31;
  const int seg = cc << 3;
  const float4 v0 = *(const float4*)(E + (size_t)row * D_DIM + seg);
  const float4 v1 = *(const float4*)(E + (size_t)row * D_DIM + seg + 4);
  float vv[8] = {v0.x, v0.y, v0.z, v0.w, v1.x, v1.y, v1.z, v1.w};
  bf16x8 hv, lv;
#pragma unroll
  for (int j = 0; j < 8; j++) {
    const unsigned short h = f2bf_rne(vv[j]);
    const float hf = __uint_as_float(((unsigned)h) << 16);
    hv[j] = (short)h;
    lv[j] = (short)f2bf_rne(vv[j] - hf);
  }
  short* base = Bp + (size_t)row * K_EFF;
  *(bf16x8*)(base + swz_slot(cc, row))      = hv;
  *(bf16x8*)(base + swz_slot(cc + 32, row)) = lv;
  *(bf16x8*)(base + swz_slot(cc + 64, row)) = hv;
}

// ---------------- e_sq (exact fp32) ----------------
__global__ __launch_bounds__(256) void esq_kernel(const float* __restrict__ E,
                                                  float* __restrict__ esq) {
  const int c = blockIdx.x * 4 + (threadIdx.x >> 6);
  const int lane = threadIdx.x & 63;
  const float4 v = *(const float4*)(E + (size_t)c * D_DIM + lane * 4);
  float s = v.x * v.x + v.y * v.y + v.z * v.z + v.w * v.w;
#pragma unroll
  for (int off = 32; off > 0; off >>= 1) s += __shfl_down(s, off);
  if (lane == 0) esq[c] = s;
}

// ---------------- MFMA dist GEMM + per-block top-2 partials ----------------
// dist = e_sq[c] - 2*dot(z,e); dot via K_EFF=768 split-bf16 GEMM.
// Explicit staging: global->VGPR (prefetched one stage ahead) -> ds_write_b128.
// Grid: x=nb (codes, fastest) so B' stays L3-resident and A' is read ~once.
__global__ __launch_bounds__(256) void argmin_gemm_kernel(
    const short* __restrict__ Ap, const short* __restrict__ Bp,
    const float* __restrict__ esq, float4* __restrict__ partials) {
  __shared__ __align__(16) union U {
    struct { short A[128 * BK]; short B[128 * BK]; } s;   // 32 KB, rows pre-swizzled
    struct { float4 red[128][2]; } r;                     // epilogue
  } u;
  __shared__ float esq_s[128];

  const int tid = threadIdx.x;
  const int nb = blockIdx.x, mb = blockIdx.y;
  const int w = tid >> 6, lane = tid & 63;
  const int wr = w >> 1, wc = w & 1;
  const int l15 = lane & 15, quad = lane >> 4;

  if (tid < 128) esq_s[tid] = esq[nb * 128 + tid];

  // per-thread global base pointers: thread handles chunks g = i*256+tid
  const short* gA[4];
  const short* gB[4];
#pragma unroll
  for (int i = 0; i < 4; i++) {
    const int g = i * 256 + tid;
    const int r = g >> 3;     // tile row 0..127
    const int c = g & 7;      // slot (swizzle baked into buffer)
    gA[i] = Ap + (size_t)(mb * 128 + r) * K_EFF + c * 8;
    gB[i] = Bp + (size_t)(nb * 128 + r) * K_EFF + c * 8;
  }

  f32x4 acc[4][4];
#pragma unroll
  for (int i = 0; i < 4; i++)
#pragma unroll
    for (int j = 0; j < 4; j++) acc[i][j] = (f32x4){0.f, 0.f, 0.f, 0.f};

  // prefetch stage 0 into registers
  bf16x8 pa[4], pb[4];
#pragma unroll
  for (int i = 0; i < 4; i++) {
    pa[i] = *(const bf16x8*)(gA[i]);
    pb[i] = *(const bf16x8*)(gB[i]);
  }

  for (int s = 0; s < STAGES; s++) {
    __syncthreads();  // previous stage's ds_reads complete before overwrite
#pragma unroll
    for (int i = 0; i < 4; i++) {
      const int g = i * 256 + tid;
      *(bf16x8*)(u.s.A + g * 8) = pa[i];
      *(bf16x8*)(u.s.B + g * 8) = pb[i];
    }
    __syncthreads();  // LDS tiles ready
    if (s + 1 < STAGES) {  // prefetch next stage; latency hides under compute below
#pragma unroll
      for (int i = 0; i < 4; i++) {
        pa[i] = *(const bf16x8*)(gA[i] + (s + 1) * BK);
        pb[i] = *(const bf16x8*)(gB[i] + (s + 1) * BK);
      }
    }
#pragma unroll
    for (int ks = 0; ks < 2; ks++) {
      bf16x8 af[4], bf[4];
#pragma unroll
      for (int ti = 0; ti < 4; ti++) {
        const int rowA = wr * 64 + ti * 16 + l15;
        const int swa = (ks * 4 + quad) ^ (rowA & 7);
        af[ti] = *(const bf16x8*)((const char*)u.s.A + rowA * 128 + swa * 16);
        const int rowB = wc * 64 + ti * 16 + l15;
        const int swb = (ks * 4 + quad) ^ (rowB & 7);
        bf[ti] = *(const bf16x8*)((const char*)u.s.B + rowB * 128 + swb * 16);
      }
#pragma unroll
      for (int ti = 0; ti < 4; ti++)
#pragma unroll
        for (int tj = 0; tj < 4; tj++)
          acc[ti][tj] = __builtin_amdgcn_mfma_f32_16x16x32_bf16(
              af[ti], bf[tj], acc[ti][tj], 0, 0, 0);
    }
  }

  __syncthreads();  // all LDS compute reads done; reuse union for reduction
  // C layout: row = quad*4 + reg, col = lane&15 (per 16x16 tile)
#pragma unroll
  for (int ti = 0; ti < 4; ti++) {
#pragma unroll
    for (int reg = 0; reg < 4; reg++) {
      float d1 = 3.4e38f, d2 = 3.4e38f;
      int i1 = 0, i2 = 0;
#pragma unroll
      for (int tj = 0; tj < 4; tj++) {
        const float dist = esq_s[wc * 64 + tj * 16 + l15] - 2.0f * acc[ti][tj][reg];
        const int c = nb * 128 + wc * 64 + tj * 16 + l15;
        top2_merge(d1, i1, d2, i2, dist, c);
      }
#pragma unroll
      for (int m = 1; m <= 8; m <<= 1) {
        const float od1 = __shfl_xor(d1, m); const int oi1 = __shfl_xor(i1, m);
        const float od2 = __shfl_xor(d2, m); const int oi2 = __shfl_xor(i2, m);
        top2_merge(d1, i1, d2, i2, od1, oi1);
        top2_merge(d1, i1, d2, i2, od2, oi2);
      }
      if (l15 == 0) {
        const int row_local = wr * 64 + ti * 16 + quad * 4 + reg;
        u.r.red[row_local][wc] =
            make_float4(d1, __int_as_float(i1), d2, __int_as_float(i2));
      }
    }
  }
  __syncthreads();
  if (tid < 128) {
    const float4 pa2 = u.r.red[tid][0];
    const float4 pb2 = u.r.red[tid][1];
    float d1 = pa2.x, d2 = pa2.z;
    int i1 = __float_as_int(pa2.y), i2 = __float_as_int(pa2.w);
    top2_merge(d1, i1, d2, i2, pb2.x, __float_as_int(pb2.y));
    top2_merge(d1, i1, d2, i2, pb2.z, __float_as_int(pb2.w));
    partials[(size_t)(mb * 128 + tid) * 64 + nb] =
        make_float4(d1, __int_as_float(i1), d2, __int_as_float(i2));
  }
}

// ---------------- merge 64 partials/row + distributed fp64 rescore ----------------
__global__ __launch_bounds__(256) void reduce_kernel(
    const float4* __restrict__ partials, const float* __restrict__ Z,
    const float* __restrict__ E, float* __restrict__ out_idx_f) {
  const int row = blockIdx.x * 4 + (threadIdx.x >> 6);
  const int lane = threadIdx.x & 63;
  const float4 p = partials[(size_t)row * 64 + lane];
  float d1 = p.x, d2 = p.z;
  int i1 = __float_as_int(p.y), i2 = __float_as_int(p.w);
#pragma unroll
  for (int m = 1; m < 64; m <<= 1) {
    const float od1 = __shfl_xor(d1, m); const int oi1 = __shfl_xor(i1, m);
    const float od2 = __shfl_xor(d2, m); const int oi2 = __shfl_xor(i2, m);
    top2_merge(d1, i1, d2, i2, od1, oi1);
    top2_merge(d1, i1, d2, i2, od2, oi2);
  }
  // all lanes hold the same global top-2; fp64 rescore split across lanes
  const float4 zv  = ((const float4*)(Z + (size_t)row * D_DIM))[lane];
  const float4 e1v = ((const float4*)(E + (size_t)i1 * D_DIM))[lane];
  const float4 e2v = ((const float4*)(E + (size_t)i2 * D_DIM))[lane];
  double a = 0.0, b = 0.0, t;
  t = (double)zv.x - (double)e1v.x; a += t * t;
  t = (double)zv.y - (double)e1v.y; a += t * t;
  t = (double)zv.z - (double)e1v.z; a += t * t;
  t = (double)zv.w - (double)e1v.w; a += t * t;
  t = (double)zv.x - (double)e2v.x; b += t * t;
  t = (double)zv.y - (double)e2v.y; b += t * t;
  t = (double)zv.z - (double)e2v.z; b += t * t;
  t = (double)zv.w - (double)e2v.w; b += t * t;
#pragma unroll
  for (int m = 1; m < 64; m <<= 1) {
    a += __shfl_xor(a, m);
    b += __shfl_xor(b, m);
  }
  if (lane == 0) {
    const int fin = (b < a || (b == a && i2 < i1)) ? i2 : i1;
    out_idx_f[row] = (float)fin;
  }
}

// ---------------- gather z_q, accumulate loss sum + counts ----------------
__global__ __launch_bounds__(256) void gather_kernel(
    const float* __restrict__ Z, const float* __restrict__ E,
    const float* __restrict__ idx_f, float* __restrict__ zq_out,
    float* __restrict__ counts, float* __restrict__ loss_sum) {
  const int row = blockIdx.x;
  const int t = threadIdx.x;
  const int c = (int)idx_f[row];
  const float e = E[(size_t)c * D_DIM + t];
  const float z = Z[(size_t)row * D_DIM + t];
  zq_out[(size_t)row * D_DIM + t] = e;
  float sq = (z - e) * (z - e);
#pragma unroll
  for (int off = 32; off > 0; off >>= 1) sq += __shfl_down(sq, off);
  __shared__ float wsum[4];
  if ((t & 63) == 0) wsum[t >> 6] = sq;
  __syncthreads();
  if (t == 0) {
    atomicAdd(loss_sum, wsum[0] + wsum[1] + wsum[2] + wsum[3]);
    atomicAdd(&counts[c], 1.0f);
  }
}

// ---------------- loss scale + perplexity ----------------
__global__ __launch_bounds__(256) void final_kernel(
    const float* __restrict__ counts, const float* __restrict__ loss_sum,
    float* __restrict__ out) {
  const int t = threadIdx.x;
  float h = 0.0f;
  for (int k = t; k < K_CB; k += 256) {
    const float p = counts[k] * (1.0f / (float)N_TOT);
    h += p * logf(p + 1e-12f);
  }
#pragma unroll
  for (int off = 32; off > 0; off >>= 1) h += __shfl_down(h, off);
  __shared__ float ws4[4];
  if ((t & 63) == 0) ws4[t >> 6] = h;
  __syncthreads();
  if (t == 0) {
    const float H = ws4[0] + ws4[1] + ws4[2] + ws4[3];
    out[OUT_LOSS] = 1.25f * loss_sum[0] * (1.0f / (float)(N_TOT * D_DIM));
    out[OUT_PERP] = expf(-H);
  }
}

extern "C" void kernel_launch(void* const* d_in, const int* in_sizes, int n_in,
                              void* d_out, int out_size, void* d_ws, size_t ws_size,
                              hipStream_t stream) {
  (void)in_sizes; (void)n_in; (void)out_size; (void)ws_size;
  const float* Z = (const float*)d_in[0];
  const float* E = (const float*)d_in[1];
  float* out = (float*)d_out;
  char* ws = (char*)d_ws;
  float* counts   = (float*)ws;                      // 32 KB
  float* loss_sum = (float*)(ws + 32768);            // 4 B
  float* esq      = (float*)(ws + 36864);            // 32 KB
  short* Ap       = (short*)(ws + 69632);            // 32768*768*2 = 50331648 B
  short* Bp       = (short*)(ws + 69632 + 50331648); // 8192*768*2  = 12582912 B
  // partials live in d_out's zq region (exactly 32768*64 float4), overwritten by gather later
  float4* partials = (float4*)d_out;

  hipMemsetAsync(ws, 0, 32772, stream);  // zero counts + loss_sum
  esq_kernel<<<dim3(K_CB / 4), dim3(256), 0, stream>>>(E, esq);
  split_z_kernel<<<dim3(N_TOT * D_DIM / 8 / 256), dim3(256), 0, stream>>>(Z, Ap);
  split_e_kernel<<<dim3(K_CB * D_DIM / 8 / 256), dim3(256), 0, stream>>>(E, Bp);
  argmin_gemm_kernel<<<dim3(K_CB / 128, N_TOT / 128), dim3(256), 0, stream>>>(
      Ap, Bp, esq, partials);
  reduce_kernel<<<dim3(N_TOT / 4), dim3(256), 0, stream>>>(partials, Z, E, out + OUT_IDX);
  gather_kernel<<<dim3(N_TOT), dim3(256), 0, stream>>>(Z, E, out + OUT_IDX, out, counts, loss_sum);
  final_kernel<<<dim3(1), dim3(256), 0, stream>>>(counts, loss_sum, out);
}